// Round 14
// baseline (239.735 us; speedup 1.0000x reference)
//
#include <hip/hip_runtime.h>
#include <hip/hip_bf16.h>

#define B_ 64
#define T_ 512
#define LOG2E 1.4426950408889634f
#define PHASE_STEPS 16
#define NPHASE (T_/PHASE_STEPS)

typedef __attribute__((ext_vector_type(8))) short short8;
typedef __attribute__((ext_vector_type(4))) float f32x4;

__device__ __forceinline__ float fast_exp2(float x){ return __builtin_amdgcn_exp2f(x); }
__device__ __forceinline__ float fast_rcp(float x){ return __builtin_amdgcn_rcpf(x); }
__device__ __forceinline__ float sigmoidf_(float x){ return fast_rcp(1.0f + fast_exp2(-x*LOG2E)); }
__device__ __forceinline__ unsigned short f2bf(float f){
  union{float f; unsigned u;} v; v.f = f;
  unsigned r = v.u + 0x7fffu + ((v.u>>16)&1u);
  return (unsigned short)(r>>16);
}
__device__ __forceinline__ float bf2f(unsigned short u){
  union{unsigned u; float f;} v; v.u = ((unsigned)u)<<16; return v.f;
}

// DPP butterfly add over 8-lane groups (aligned): xor1, xor2, then cross-quad mirror.
template<int CTRL>
__device__ __forceinline__ float dpp_xadd(float x){
  int y = __builtin_amdgcn_update_dpp(0, __float_as_int(x), CTRL, 0xf, 0xf, true);
  return x + __int_as_float(y);
}
__device__ __forceinline__ float dpp_sum8(float x){
  x = dpp_xadd<0xB1>(x);   // quad_perm [1,0,3,2]  (xor 1)
  x = dpp_xadd<0x4E>(x);   // quad_perm [2,3,0,1]  (xor 2)
  x = dpp_xadd<0x141>(x);  // row_half_mirror      (cross-quad within 8)
  return x;
}

// LDS-only barrier: completes ds ops, then wave-barrier; does NOT drain vmcnt.
__device__ __forceinline__ void lds_barrier(){
  asm volatile("s_waitcnt lgkmcnt(0)" ::: "memory");
  __builtin_amdgcn_s_barrier();
  asm volatile("" ::: "memory");
}

// ---------------- Kernel 1: blocks 0..511 = proj1; blocks 512..767 = weight prep -------
// P1 layout per (t,b): 12 floats: 0..2 = k*LOG2E, 3..5 = 0.1*v, 6..8 = 0.1*sigmoid(g).
__global__ __launch_bounds__(256) void k_proj1(const float* __restrict__ X,
    const float* __restrict__ Wk, const float* __restrict__ bk,
    const float* __restrict__ Ww, const float* __restrict__ bw,
    const float* __restrict__ Wg, const float* __restrict__ bg,
    float* __restrict__ P1,
    const float* __restrict__ W1o,
    const float* __restrict__ W2k, const float* __restrict__ W2w, const float* __restrict__ W2g,
    unsigned short* __restrict__ W1oTb, unsigned short* __restrict__ W2cTb)
{
  __shared__ __align__(16) float A[64*132];
  __shared__ __align__(16) float WcT[9*132];
  __shared__ float bb[9];
  int tid = threadIdx.x;
  if (blockIdx.x >= 512){            // ---- prep path ----
    int idx = ((int)blockIdx.x - 512)*256 + tid;
    if (idx < 65536){
      int n = idx >> 7, k = idx & 127;
      W1oTb[idx] = f2bf(W1o[k*512 + n]);
    }
    if (idx < 8192){
      int j = idx >> 9, c = idx & 511;
      float v = 0.f;
      if (j < 3) v = W2k[c*3 + j];
      else if (j < 6) v = W2w[c*3 + j - 3];
      else if (j < 9) v = W2g[c*3 + j - 6];
      W2cTb[idx] = f2bf(v);
    }
    return;
  }
  long r0 = (long)blockIdx.x * 64;
  const float4* X4 = (const float4*)(X + r0*128);
  #pragma unroll
  for (int it=0; it<8; ++it){
    int f4 = tid + it*256;
    float4 v = X4[f4];
    int f = f4*4; int row = f>>7; int k = f&127;
    *(float4*)&A[row*132+k] = v;
  }
  #pragma unroll
  for (int it=0; it<5; ++it){
    int w0 = tid + it*256;
    if (w0 < 1152){
      int k = w0/9, j = w0%9;
      float val;
      if (j<3) val = Wk[k*3+j]; else if (j<6) val = Ww[k*3+j-3]; else val = Wg[k*3+j-6];
      WcT[j*132+k] = val;
    }
  }
  if (tid < 9){
    float v; if (tid<3) v = bk[tid]; else if (tid<6) v = bw[tid-3]; else v = bg[tid-6];
    bb[tid] = v;
  }
  __syncthreads();
  for (int o = tid; o < 576; o += 256){
    int row = o/9, j = o%9;
    const f32x4* Ar = (const f32x4*)(A + row*132);
    const f32x4* Wr = (const f32x4*)(WcT + j*132);
    f32x4 acc4 = {0.f,0.f,0.f,0.f};
    #pragma unroll
    for (int k4=0;k4<32;++k4){
      f32x4 a = Ar[k4], wv = Wr[k4];
      acc4[0]=fmaf(a[0],wv[0],acc4[0]);
      acc4[1]=fmaf(a[1],wv[1],acc4[1]);
      acc4[2]=fmaf(a[2],wv[2],acc4[2]);
      acc4[3]=fmaf(a[3],wv[3],acc4[3]);
    }
    float acc = bb[j] + (acc4[0]+acc4[1]) + (acc4[2]+acc4[3]);
    if (j<3) acc *= LOG2E;
    else if (j<6) acc *= 0.1f;
    else acc = 0.1f * sigmoidf_(acc);
    long r = r0 + row;
    int b = (int)(r >> 9); int t = (int)(r & 511);
    int bh = b >> 5, bl = b & 31;
    P1[(((long)bh*512 + t)*32 + bl)*12 + j] = acc;
  }
}

// ---------------- LDS-staged slim scan (round-8 body, byte-identical: 53.0 µs) ----------
template<int STORE_SM>
__device__ __forceinline__ void scan_slim(const float* __restrict__ P,
                                          float* __restrict__ Out, int bh)
{
  __shared__ __align__(16) float buf[2][PHASE_STEPS*32*12];   // 2 x 24 KB
  int tid = threadIdx.x;
  int wv = tid >> 6, lane = tid & 63;
  const float* Pb = P + (long)bh*512*384;
  if (wv == 8){
    #pragma unroll 1
    for (int p = 0; p < NPHASE; ++p){
      const float4* s4 = (const float4*)Pb + (long)p*1536;
      float4* d4 = (float4*)buf[p&1];
      #pragma unroll
      for (int c=0;c<2;++c){
        float4 tmp[12];
        #pragma unroll
        for (int i=0;i<12;++i) tmp[i] = s4[lane + (c*12+i)*64];
        #pragma unroll
        for (int i=0;i<12;++i) d4[lane + (c*12+i)*64] = tmp[i];
      }
      lds_barrier();
    }
    return;
  }
  if (lane >= 32) return;     // half-active waves: 2 waves/SIMD at same issue cost
  int g = lane >> 3, slot = lane & 7;
  int bl = wv*4 + g;
  int batch = bh*32 + bl;
  float* So = Out + ((long)batch*8 + slot)*4;    // + t*2048 per step
  float m0=0.f, m1=0.f, m2=0.f;
  f32x4 pfa[4], pfb[4]; float pfc[4];
  lds_barrier();   // buf0 ready
  #pragma unroll 1
  for (int p = 0; p < NPHASE; ++p){
    const float* bp = buf[p&1] + bl*12;
    const f32x4* bp4 = (const f32x4*)bp;         // step stride: 96 f32x4 (384 floats)
    #pragma unroll
    for (int u=0;u<3;++u){
      pfa[u]=bp4[u*96]; pfb[u]=bp4[u*96+1]; pfc[u]=bp[u*384+8];
    }
    #pragma unroll
    for (int s=0;s<PHASE_STEPS;++s){
      f32x4 A0=pfa[s&3], A1=pfb[s&3]; float e2=pfc[s&3];
      if (s+3 < PHASE_STEPS){
        int i3=(s+3)&3;
        pfa[i3]=bp4[(s+3)*96]; pfb[i3]=bp4[(s+3)*96+1]; pfc[i3]=bp[(s+3)*384+8];
      }
      float sc = fmaf(m2, A0[2], fmaf(m1, A0[1], m0*A0[0]));
      float pe = fast_exp2(sc);
      float S = dpp_sum8(pe);
      float rinv = fast_rcp(S);
      float w = pe * rinv;
      if (STORE_SM){
        f32x4 sv; sv[0]=pe; sv[1]=m0; sv[2]=m1; sv[3]=m2;   // pre-update m
        *(f32x4*)(So + (long)(p*PHASE_STEPS+s)*2048) = sv;
      } else if (p == NPHASE-1 && s == PHASE_STEPS-1){
        float r0 = dpp_sum8(pe*m0);
        float r1 = dpp_sum8(pe*m1);
        float r2 = dpp_sum8(pe*m2);
        float rsel = (slot==0) ? r0 : ((slot==1) ? r1 : r2);
        rsel *= rinv;
        if (slot < 3) Out[slot*64 + batch] = rsel;
      }
      float v0=A0[3], v1=A1[0], v2=A1[1], e0=A1[2], e1=A1[3];
      m0 = fmaf(w, fmaf(-e0, m0, v0), m0);
      m1 = fmaf(w, fmaf(-e1, m1, v1), m1);
      m2 = fmaf(w, fmaf(-e2, m2, v2), m2);
    }
    if (p < NPHASE-1) lds_barrier();
  }
}

__global__ __launch_bounds__(576) void k_scan1(const float* __restrict__ P1,
                                               float* __restrict__ SM)
{
  scan_slim<1>(P1, SM, (int)blockIdx.x);
}

// ---------------- Kernel 3: MFMA fused, 64-ROW BLOCKS, 512 THREADS (8 waves) ------------
// vs round-8 (64-row, 256 thr): same 512 blocks, same W1oTb/X/SM traffic, same ~74 KB LDS
// (2 blocks/CU) — but 8 waves/block => 4 waves/SIMD (2x TLP) at IDENTICAL bandwidth.
// Each wave covers 64 output columns (tt<4 in C, q2<2 in D). Unconfounded occupancy test.
__global__ __launch_bounds__(512, 4) void k_fused(const float* __restrict__ X,
    const float* __restrict__ W1o, const float* __restrict__ b1o,
    const float* __restrict__ SM,
    const unsigned short* __restrict__ W1oTb, const unsigned short* __restrict__ W2cTb,
    const float* __restrict__ b2k, const float* __restrict__ b2w, const float* __restrict__ b2g,
    float* __restrict__ P2, float* __restrict__ O1last)
{
  __shared__ __align__(16) float rdS[192];                 // 64 rows x 3
  __shared__ __align__(16) unsigned short o1b[64*520];     // 66.5 KB
  __shared__ __align__(16) float pSum[8*16*16];            // 8 KB (8 wave-partials)
  int tid = threadIdx.x;
  int w = tid >> 6, lane = tid & 63;
  int n16 = lane & 15, g4 = lane >> 4;
  long r0 = (long)blockIdx.x * 64;
  int b = (int)(r0 >> 9); int t0 = (int)(r0 & 511);

  // Phase A: SM read-vector reduction for 64 rows x 8 slots (512 tasks, one pass)
  {
    int i = tid >> 3;
    int slot = tid & 7;
    f32x4 v = *(const f32x4*)(SM + (((long)(t0+i)*64 + b)*8 + slot)*4);
    float S   = dpp_sum8(v[0]);
    float r0v = dpp_sum8(v[0]*v[1]);
    float r1v = dpp_sum8(v[0]*v[2]);
    float r2v = dpp_sum8(v[0]*v[3]);
    float rinv = fast_rcp(S);
    float rsel = (slot==0) ? r0v : ((slot==1) ? r1v : r2v);
    if (slot < 3) rdS[i*3+slot] = rsel*rinv;
  }

  // Phase B: A-fragments for 4 row-tiles (rows r0 + rt*16 + n16; same in every wave)
  short8 afr[4][4];
  #pragma unroll
  for (int rt=0; rt<4; ++rt){
    const float* Xrow = X + (r0 + rt*16 + n16)*128;
    #pragma unroll
    for (int q=0;q<4;++q){
      f32x4 x0 = *(const f32x4*)(Xrow + q*32 + g4*8);
      f32x4 x1 = *(const f32x4*)(Xrow + q*32 + g4*8 + 4);
      short8 a;
      a[0]=(short)f2bf(x0[0]); a[1]=(short)f2bf(x0[1]);
      a[2]=(short)f2bf(x0[2]); a[3]=(short)f2bf(x0[3]);
      a[4]=(short)f2bf(x1[0]); a[5]=(short)f2bf(x1[1]);
      a[6]=(short)f2bf(x1[2]); a[7]=(short)f2bf(x1[3]);
      afr[rt][q]=a;
    }
  }
  __syncthreads();

  // Phase C: z1 = x@W1o (+bias +rd·wr), o1 = sigmoid -> o1b. W1oTb streamed ONCE/block.
  // Wave w owns columns [w*64, w*64+64): tt<4.
  #pragma unroll
  for (int tt=0; tt<4; ++tt){
    int gc = w*64 + tt*16 + n16;
    short8 bf[4];
    #pragma unroll
    for (int q=0;q<4;++q)
      bf[q] = *(const short8*)(W1oTb + gc*128 + q*32 + g4*8);
    float bias = b1o[gc];
    float wr0 = W1o[128*512+gc], wr1 = W1o[129*512+gc], wr2 = W1o[130*512+gc];
    #pragma unroll
    for (int rt=0; rt<4; ++rt){
      f32x4 acc = {0.f,0.f,0.f,0.f};
      #pragma unroll
      for (int q=0;q<4;++q)
        acc = __builtin_amdgcn_mfma_f32_16x16x32_bf16(afr[rt][q], bf[q], acc, 0,0,0);
      f32x4 ra = *(const f32x4*)(rdS + rt*48 + g4*12);
      f32x4 rb = *(const f32x4*)(rdS + rt*48 + g4*12 + 4);
      f32x4 rc = *(const f32x4*)(rdS + rt*48 + g4*12 + 8);
      float rd0[4] = { ra[0], ra[3], rb[2], rc[1] };
      float rd1[4] = { ra[1], rb[0], rb[3], rc[2] };
      float rd2[4] = { ra[2], rb[1], rc[0], rc[3] };
      #pragma unroll
      for (int reg=0; reg<4; ++reg){
        int rowloc = rt*16 + g4*4 + reg;
        float z = acc[reg] + bias + rd0[reg]*wr0 + rd1[reg]*wr1 + rd2[reg]*wr2;
        float o1 = sigmoidf_(z);
        o1b[rowloc*520 + gc] = f2bf(o1);
        if (t0 == 448 && rowloc == 63) O1last[b*512 + gc] = o1;   // t = 511
      }
    }
  }
  __syncthreads();

  // Phase D: P2 = o1 @ W2c, per 16-row group. Wave w covers kk in [w*64, w*64+64): q2<2.
  #pragma unroll 1
  for (int rt2=0; rt2<4; ++rt2){
    f32x4 accP = {0.f,0.f,0.f,0.f};
    #pragma unroll
    for (int q2=0; q2<2; ++q2){
      int kk = w*64 + q2*32;
      short8 a2 = *(const short8*)(o1b + (rt2*16 + n16)*520 + kk + g4*8);
      short8 bb2 = *(const short8*)(W2cTb + n16*512 + kk + g4*8);
      accP = __builtin_amdgcn_mfma_f32_16x16x32_bf16(a2, bb2, accP, 0,0,0);
    }
    #pragma unroll
    for (int reg=0;reg<4;++reg){
      int rowloc = g4*4+reg;
      pSum[w*256 + rowloc*16 + n16] = accP[reg];
    }
    __syncthreads();
    if (tid < 144){
      int r = tid/9, j = tid%9;
      float s = 0.f;
      #pragma unroll
      for (int ww=0; ww<8; ++ww) s += pSum[ww*256 + r*16 + j];
      float outv;
      if (j<3){ s += b2k[j]; outv = s*LOG2E; }
      else if (j<6){ s += b2w[j-3]; outv = 0.1f*s; }
      else { s += b2g[j-6]; outv = 0.1f*sigmoidf_(s); }
      int t = t0 + rt2*16 + r;
      int bh = b >> 5, bl = b & 31;
      P2[(((long)bh*512 + t)*32 + bl)*12 + j] = outv;
    }
    __syncthreads();
  }
}

// ---------------- Kernel 4: blocks 0,1 = scan2; blocks 2..65 = Opart --------------------
__global__ __launch_bounds__(576) void k_scan2_opart(const float* __restrict__ P2,
    float* __restrict__ R2F,
    const float* __restrict__ O1last, const float* __restrict__ W2o,
    const float* __restrict__ b2o, float* __restrict__ Opart)
{
  if (blockIdx.x < 2){
    scan_slim<0>(P2, R2F, (int)blockIdx.x);
    return;
  }
  __shared__ __align__(16) float s2[512];
  int b = blockIdx.x - 2; int tid = threadIdx.x;
  if (tid < 128)
    ((float4*)s2)[tid] = ((const float4*)(O1last + b*512))[tid];
  __syncthreads();
  if (tid < 128){
    float acc = b2o[tid];
    #pragma unroll 8
    for (int n=0;n<512;++n) acc = fmaf(s2[n], W2o[n*128+tid], acc);
    Opart[b*128+tid] = acc;
  }
}

// ---------------- Kernel 5: out = sigmoid(Opart + read2 @ W2o[512:515]) -----------------
__global__ __launch_bounds__(256) void k_final(const float* __restrict__ Opart,
    const float* __restrict__ R2F, const float* __restrict__ W2o,
    float* __restrict__ out)
{
  int idx = blockIdx.x*256 + threadIdx.x;
  if (idx < 8192){
    int b = idx >> 7; int o = idx & 127;
    float r0 = R2F[b], r1 = R2F[64+b], r2 = R2F[128+b];
    float v = Opart[idx]
            + r0*W2o[512*128+o] + r1*W2o[513*128+o] + r2*W2o[514*128+o];
    out[idx] = sigmoidf_(v);
  }
}

extern "C" void kernel_launch(void* const* d_in, const int* in_sizes, int n_in,
                              void* d_out, int out_size, void* d_ws, size_t ws_size,
                              hipStream_t stream)
{
  const float* X  = (const float*)d_in[0];
  const float* W1k= (const float*)d_in[1]; const float* b1k=(const float*)d_in[2];
  const float* W1w= (const float*)d_in[3]; const float* b1w=(const float*)d_in[4];
  const float* W1g= (const float*)d_in[5]; const float* b1g=(const float*)d_in[6];
  const float* W1o= (const float*)d_in[7]; const float* b1o=(const float*)d_in[8];
  const float* W2k= (const float*)d_in[9]; const float* b2k=(const float*)d_in[10];
  const float* W2w= (const float*)d_in[11]; const float* b2w=(const float*)d_in[12];
  const float* W2g= (const float*)d_in[13]; const float* b2g=(const float*)d_in[14];
  const float* W2o= (const float*)d_in[15]; const float* b2o=(const float*)d_in[16];

  float* ws = (float*)d_ws;
  float* P1     = ws;                 // 2*512*32*12    = 393216 floats
  float* SM     = P1 + 393216;        // 512*64*8*4     = 1048576 floats
  float* O1last = SM + 1048576;       // 64*512         = 32768
  float* R2F    = O1last + 32768;     // 3*64           = 192
  float* Opart  = R2F + 192;          // 64*128         = 8192
  unsigned short* W1oTb = (unsigned short*)(Opart + 8192);  // 512*128 bf16
  unsigned short* W2cTb = W1oTb + 65536;                    // 16*512 bf16
  float* P2     = P1;   // alias: P1 dead after k_scan1 (k_fused reads only X & SM)
  float* out    = (float*)d_out;

  hipLaunchKernelGGL(k_proj1, dim3(768), dim3(256), 0, stream,
                     X, W1k,b1k, W1w,b1w, W1g,b1g, P1,
                     W1o, W2k, W2w, W2g, W1oTb, W2cTb);
  hipLaunchKernelGGL(k_scan1, dim3(2), dim3(576), 0, stream, P1, SM);
  hipLaunchKernelGGL(k_fused, dim3(512), dim3(512), 0, stream,
                     X, W1o, b1o, SM, W1oTb, W2cTb, b2k, b2w, b2g, P2, O1last);
  hipLaunchKernelGGL(k_scan2_opart, dim3(66), dim3(576), 0, stream,
                     P2, R2F, O1last, W2o, b2o, Opart);
  hipLaunchKernelGGL(k_final, dim3(32), dim3(256), 0, stream,
                     Opart, R2F, W2o, out);
}

// Round 15
// 225.588 us; speedup vs baseline: 1.0627x; 1.0627x over previous
//
#include <hip/hip_runtime.h>
#include <hip/hip_bf16.h>

#define B_ 64
#define T_ 512
#define LOG2E 1.4426950408889634f
#define PHASE_STEPS 16
#define NPHASE (T_/PHASE_STEPS)

typedef __attribute__((ext_vector_type(8))) short short8;
typedef __attribute__((ext_vector_type(4))) float f32x4;

__device__ __forceinline__ float fast_exp2(float x){ return __builtin_amdgcn_exp2f(x); }
__device__ __forceinline__ float fast_rcp(float x){ return __builtin_amdgcn_rcpf(x); }
__device__ __forceinline__ float sigmoidf_(float x){ return fast_rcp(1.0f + fast_exp2(-x*LOG2E)); }
__device__ __forceinline__ unsigned short f2bf(float f){
  union{float f; unsigned u;} v; v.f = f;
  unsigned r = v.u + 0x7fffu + ((v.u>>16)&1u);
  return (unsigned short)(r>>16);
}
__device__ __forceinline__ float bf2f(unsigned short u){
  union{unsigned u; float f;} v; v.u = ((unsigned)u)<<16; return v.f;
}

// DPP butterfly add over 8-lane groups (aligned): xor1, xor2, then cross-quad mirror.
template<int CTRL>
__device__ __forceinline__ float dpp_xadd(float x){
  int y = __builtin_amdgcn_update_dpp(0, __float_as_int(x), CTRL, 0xf, 0xf, true);
  return x + __int_as_float(y);
}
__device__ __forceinline__ float dpp_sum8(float x){
  x = dpp_xadd<0xB1>(x);   // quad_perm [1,0,3,2]  (xor 1)
  x = dpp_xadd<0x4E>(x);   // quad_perm [2,3,0,1]  (xor 2)
  x = dpp_xadd<0x141>(x);  // row_half_mirror      (cross-quad within 8)
  return x;
}

// LDS-only barrier: completes ds ops, then wave-barrier; does NOT drain vmcnt.
__device__ __forceinline__ void lds_barrier(){
  asm volatile("s_waitcnt lgkmcnt(0)" ::: "memory");
  __builtin_amdgcn_s_barrier();
  asm volatile("" ::: "memory");
}

// ---------------- Kernel 1: blocks 0..511 = proj1; blocks 512..767 = weight prep -------
// P1 layout per (t,b): 12 floats: 0..2 = k*LOG2E, 3..5 = 0.1*v, 6..8 = 0.1*sigmoid(g).
__global__ __launch_bounds__(256) void k_proj1(const float* __restrict__ X,
    const float* __restrict__ Wk, const float* __restrict__ bk,
    const float* __restrict__ Ww, const float* __restrict__ bw,
    const float* __restrict__ Wg, const float* __restrict__ bg,
    float* __restrict__ P1,
    const float* __restrict__ W1o,
    const float* __restrict__ W2k, const float* __restrict__ W2w, const float* __restrict__ W2g,
    unsigned short* __restrict__ W1oTb, unsigned short* __restrict__ W2cTb)
{
  __shared__ __align__(16) float A[64*132];
  __shared__ __align__(16) float WcT[9*132];
  __shared__ float bb[9];
  int tid = threadIdx.x;
  if (blockIdx.x >= 512){            // ---- prep path ----
    int idx = ((int)blockIdx.x - 512)*256 + tid;
    if (idx < 65536){
      int n = idx >> 7, k = idx & 127;
      W1oTb[idx] = f2bf(W1o[k*512 + n]);
    }
    if (idx < 8192){
      int j = idx >> 9, c = idx & 511;
      float v = 0.f;
      if (j < 3) v = W2k[c*3 + j];
      else if (j < 6) v = W2w[c*3 + j - 3];
      else if (j < 9) v = W2g[c*3 + j - 6];
      W2cTb[idx] = f2bf(v);
    }
    return;
  }
  long r0 = (long)blockIdx.x * 64;
  const float4* X4 = (const float4*)(X + r0*128);
  #pragma unroll
  for (int it=0; it<8; ++it){
    int f4 = tid + it*256;
    float4 v = X4[f4];
    int f = f4*4; int row = f>>7; int k = f&127;
    *(float4*)&A[row*132+k] = v;
  }
  #pragma unroll
  for (int it=0; it<5; ++it){
    int w0 = tid + it*256;
    if (w0 < 1152){
      int k = w0/9, j = w0%9;
      float val;
      if (j<3) val = Wk[k*3+j]; else if (j<6) val = Ww[k*3+j-3]; else val = Wg[k*3+j-6];
      WcT[j*132+k] = val;
    }
  }
  if (tid < 9){
    float v; if (tid<3) v = bk[tid]; else if (tid<6) v = bw[tid-3]; else v = bg[tid-6];
    bb[tid] = v;
  }
  __syncthreads();
  for (int o = tid; o < 576; o += 256){
    int row = o/9, j = o%9;
    const f32x4* Ar = (const f32x4*)(A + row*132);
    const f32x4* Wr = (const f32x4*)(WcT + j*132);
    f32x4 acc4 = {0.f,0.f,0.f,0.f};
    #pragma unroll
    for (int k4=0;k4<32;++k4){
      f32x4 a = Ar[k4], wv = Wr[k4];
      acc4[0]=fmaf(a[0],wv[0],acc4[0]);
      acc4[1]=fmaf(a[1],wv[1],acc4[1]);
      acc4[2]=fmaf(a[2],wv[2],acc4[2]);
      acc4[3]=fmaf(a[3],wv[3],acc4[3]);
    }
    float acc = bb[j] + (acc4[0]+acc4[1]) + (acc4[2]+acc4[3]);
    if (j<3) acc *= LOG2E;
    else if (j<6) acc *= 0.1f;
    else acc = 0.1f * sigmoidf_(acc);
    long r = r0 + row;
    int b = (int)(r >> 9); int t = (int)(r & 511);
    int bh = b >> 5, bl = b & 31;
    P1[(((long)bh*512 + t)*32 + bl)*12 + j] = acc;
  }
}

// ---------------- LDS-staged slim scan (round-8 body, byte-identical: 53.0 µs) ----------
template<int STORE_SM>
__device__ __forceinline__ void scan_slim(const float* __restrict__ P,
                                          float* __restrict__ Out, int bh)
{
  __shared__ __align__(16) float buf[2][PHASE_STEPS*32*12];   // 2 x 24 KB
  int tid = threadIdx.x;
  int wv = tid >> 6, lane = tid & 63;
  const float* Pb = P + (long)bh*512*384;
  if (wv == 8){
    #pragma unroll 1
    for (int p = 0; p < NPHASE; ++p){
      const float4* s4 = (const float4*)Pb + (long)p*1536;
      float4* d4 = (float4*)buf[p&1];
      #pragma unroll
      for (int c=0;c<2;++c){
        float4 tmp[12];
        #pragma unroll
        for (int i=0;i<12;++i) tmp[i] = s4[lane + (c*12+i)*64];
        #pragma unroll
        for (int i=0;i<12;++i) d4[lane + (c*12+i)*64] = tmp[i];
      }
      lds_barrier();
    }
    return;
  }
  if (lane >= 32) return;     // half-active waves: 2 waves/SIMD at same issue cost
  int g = lane >> 3, slot = lane & 7;
  int bl = wv*4 + g;
  int batch = bh*32 + bl;
  float* So = Out + ((long)batch*8 + slot)*4;    // + t*2048 per step
  float m0=0.f, m1=0.f, m2=0.f;
  f32x4 pfa[4], pfb[4]; float pfc[4];
  lds_barrier();   // buf0 ready
  #pragma unroll 1
  for (int p = 0; p < NPHASE; ++p){
    const float* bp = buf[p&1] + bl*12;
    const f32x4* bp4 = (const f32x4*)bp;         // step stride: 96 f32x4 (384 floats)
    #pragma unroll
    for (int u=0;u<3;++u){
      pfa[u]=bp4[u*96]; pfb[u]=bp4[u*96+1]; pfc[u]=bp[u*384+8];
    }
    #pragma unroll
    for (int s=0;s<PHASE_STEPS;++s){
      f32x4 A0=pfa[s&3], A1=pfb[s&3]; float e2=pfc[s&3];
      if (s+3 < PHASE_STEPS){
        int i3=(s+3)&3;
        pfa[i3]=bp4[(s+3)*96]; pfb[i3]=bp4[(s+3)*96+1]; pfc[i3]=bp[(s+3)*384+8];
      }
      float sc = fmaf(m2, A0[2], fmaf(m1, A0[1], m0*A0[0]));
      float pe = fast_exp2(sc);
      float S = dpp_sum8(pe);
      float rinv = fast_rcp(S);
      float w = pe * rinv;
      if (STORE_SM){
        f32x4 sv; sv[0]=pe; sv[1]=m0; sv[2]=m1; sv[3]=m2;   // pre-update m
        *(f32x4*)(So + (long)(p*PHASE_STEPS+s)*2048) = sv;
      } else if (p == NPHASE-1 && s == PHASE_STEPS-1){
        float r0 = dpp_sum8(pe*m0);
        float r1 = dpp_sum8(pe*m1);
        float r2 = dpp_sum8(pe*m2);
        float rsel = (slot==0) ? r0 : ((slot==1) ? r1 : r2);
        rsel *= rinv;
        if (slot < 3) Out[slot*64 + batch] = rsel;
      }
      float v0=A0[3], v1=A1[0], v2=A1[1], e0=A1[2], e1=A1[3];
      m0 = fmaf(w, fmaf(-e0, m0, v0), m0);
      m1 = fmaf(w, fmaf(-e1, m1, v1), m1);
      m2 = fmaf(w, fmaf(-e2, m2, v2), m2);
    }
    if (p < NPHASE-1) lds_barrier();
  }
}

__global__ __launch_bounds__(576) void k_scan1(const float* __restrict__ P1,
                                               float* __restrict__ SM)
{
  scan_slim<1>(P1, SM, (int)blockIdx.x);
}

// ---------------- Kernel 3: MFMA fused, 64-ROW BLOCKS (512 blocks) — round-8, proven ----
__global__ __launch_bounds__(256) void k_fused(const float* __restrict__ X,
    const float* __restrict__ W1o, const float* __restrict__ b1o,
    const float* __restrict__ SM,
    const unsigned short* __restrict__ W1oTb, const unsigned short* __restrict__ W2cTb,
    const float* __restrict__ b2k, const float* __restrict__ b2w, const float* __restrict__ b2g,
    float* __restrict__ P2, float* __restrict__ O1last)
{
  __shared__ __align__(16) float rdS[192];                 // 64 rows x 3
  __shared__ __align__(16) unsigned short o1b[64*520];     // 66.5 KB
  __shared__ __align__(16) float pSum[4*16*16];            // 4 KB, reused per 16-row group
  int tid = threadIdx.x;
  int w = tid >> 6, lane = tid & 63;
  int n16 = lane & 15, g4 = lane >> 4;
  long r0 = (long)blockIdx.x * 64;
  int b = (int)(r0 >> 9); int t0 = (int)(r0 & 511);

  // Phase A: SM read-vector reduction for 64 rows x 8 slots (all 256 threads, 2 halves)
  #pragma unroll
  for (int half=0; half<2; ++half){
    int i = (tid >> 3) + half*32;
    int slot = tid & 7;
    f32x4 v = *(const f32x4*)(SM + (((long)(t0+i)*64 + b)*8 + slot)*4);
    float S   = dpp_sum8(v[0]);
    float r0v = dpp_sum8(v[0]*v[1]);
    float r1v = dpp_sum8(v[0]*v[2]);
    float r2v = dpp_sum8(v[0]*v[3]);
    float rinv = fast_rcp(S);
    float rsel = (slot==0) ? r0v : ((slot==1) ? r1v : r2v);
    if (slot < 3) rdS[i*3+slot] = rsel*rinv;
  }

  // Phase B: A-fragments for 4 row-tiles (rows r0 + rt*16 + n16)
  short8 afr[4][4];
  #pragma unroll
  for (int rt=0; rt<4; ++rt){
    const float* Xrow = X + (r0 + rt*16 + n16)*128;
    #pragma unroll
    for (int q=0;q<4;++q){
      f32x4 x0 = *(const f32x4*)(Xrow + q*32 + g4*8);
      f32x4 x1 = *(const f32x4*)(Xrow + q*32 + g4*8 + 4);
      short8 a;
      a[0]=(short)f2bf(x0[0]); a[1]=(short)f2bf(x0[1]);
      a[2]=(short)f2bf(x0[2]); a[3]=(short)f2bf(x0[3]);
      a[4]=(short)f2bf(x1[0]); a[5]=(short)f2bf(x1[1]);
      a[6]=(short)f2bf(x1[2]); a[7]=(short)f2bf(x1[3]);
      afr[rt][q]=a;
    }
  }
  __syncthreads();

  // Phase C: z1 = x@W1o (+bias +rd·wr), o1 = sigmoid -> o1b. W1oTb streamed ONCE.
  #pragma unroll
  for (int tt=0; tt<8; ++tt){
    int gc = w*128 + tt*16 + n16;
    short8 bf[4];
    #pragma unroll
    for (int q=0;q<4;++q)
      bf[q] = *(const short8*)(W1oTb + gc*128 + q*32 + g4*8);
    float bias = b1o[gc];
    float wr0 = W1o[128*512+gc], wr1 = W1o[129*512+gc], wr2 = W1o[130*512+gc];
    #pragma unroll
    for (int rt=0; rt<4; ++rt){
      f32x4 acc = {0.f,0.f,0.f,0.f};
      #pragma unroll
      for (int q=0;q<4;++q)
        acc = __builtin_amdgcn_mfma_f32_16x16x32_bf16(afr[rt][q], bf[q], acc, 0,0,0);
      f32x4 ra = *(const f32x4*)(rdS + rt*48 + g4*12);
      f32x4 rb = *(const f32x4*)(rdS + rt*48 + g4*12 + 4);
      f32x4 rc = *(const f32x4*)(rdS + rt*48 + g4*12 + 8);
      float rd0[4] = { ra[0], ra[3], rb[2], rc[1] };
      float rd1[4] = { ra[1], rb[0], rb[3], rc[2] };
      float rd2[4] = { ra[2], rb[1], rc[0], rc[3] };
      #pragma unroll
      for (int reg=0; reg<4; ++reg){
        int rowloc = rt*16 + g4*4 + reg;
        float z = acc[reg] + bias + rd0[reg]*wr0 + rd1[reg]*wr1 + rd2[reg]*wr2;
        float o1 = sigmoidf_(z);
        o1b[rowloc*520 + gc] = f2bf(o1);
        if (t0 == 448 && rowloc == 63) O1last[b*512 + gc] = o1;   // t = 511
      }
    }
  }
  __syncthreads();

  // Phase D: P2 = o1 @ W2c, per 16-row group (pSum reused)
  #pragma unroll 1
  for (int rt2=0; rt2<4; ++rt2){
    f32x4 accP = {0.f,0.f,0.f,0.f};
    #pragma unroll
    for (int q2=0; q2<4; ++q2){
      int kk = w*128 + q2*32;
      short8 a2 = *(const short8*)(o1b + (rt2*16 + n16)*520 + kk + g4*8);
      short8 bb2 = *(const short8*)(W2cTb + n16*512 + kk + g4*8);
      accP = __builtin_amdgcn_mfma_f32_16x16x32_bf16(a2, bb2, accP, 0,0,0);
    }
    #pragma unroll
    for (int reg=0;reg<4;++reg){
      int rowloc = g4*4+reg;
      pSum[w*256 + rowloc*16 + n16] = accP[reg];
    }
    __syncthreads();
    if (tid < 144){
      int r = tid/9, j = tid%9;
      float s = pSum[r*16+j] + pSum[256+r*16+j] + pSum[512+r*16+j] + pSum[768+r*16+j];
      float outv;
      if (j<3){ s += b2k[j]; outv = s*LOG2E; }
      else if (j<6){ s += b2w[j-3]; outv = 0.1f*s; }
      else { s += b2g[j-6]; outv = 0.1f*sigmoidf_(s); }
      int t = t0 + rt2*16 + r;
      int bh = b >> 5, bl = b & 31;
      P2[(((long)bh*512 + t)*32 + bl)*12 + j] = outv;
    }
    __syncthreads();
  }
}

// ---------------- Kernel 4: blocks 0,1 = scan2; blocks 2..65 = Opart --------------------
__global__ __launch_bounds__(576) void k_scan2_opart(const float* __restrict__ P2,
    float* __restrict__ R2F,
    const float* __restrict__ O1last, const float* __restrict__ W2o,
    const float* __restrict__ b2o, float* __restrict__ Opart)
{
  if (blockIdx.x < 2){
    scan_slim<0>(P2, R2F, (int)blockIdx.x);
    return;
  }
  __shared__ __align__(16) float s2[512];
  int b = blockIdx.x - 2; int tid = threadIdx.x;
  if (tid < 128)
    ((float4*)s2)[tid] = ((const float4*)(O1last + b*512))[tid];
  __syncthreads();
  if (tid < 128){
    float acc = b2o[tid];
    #pragma unroll 8
    for (int n=0;n<512;++n) acc = fmaf(s2[n], W2o[n*128+tid], acc);
    Opart[b*128+tid] = acc;
  }
}

// ---------------- Kernel 5: out = sigmoid(Opart + read2 @ W2o[512:515]) -----------------
__global__ __launch_bounds__(256) void k_final(const float* __restrict__ Opart,
    const float* __restrict__ R2F, const float* __restrict__ W2o,
    float* __restrict__ out)
{
  int idx = blockIdx.x*256 + threadIdx.x;
  if (idx < 8192){
    int b = idx >> 7; int o = idx & 127;
    float r0 = R2F[b], r1 = R2F[64+b], r2 = R2F[128+b];
    float v = Opart[idx]
            + r0*W2o[512*128+o] + r1*W2o[513*128+o] + r2*W2o[514*128+o];
    out[idx] = sigmoidf_(v);
  }
}

extern "C" void kernel_launch(void* const* d_in, const int* in_sizes, int n_in,
                              void* d_out, int out_size, void* d_ws, size_t ws_size,
                              hipStream_t stream)
{
  const float* X  = (const float*)d_in[0];
  const float* W1k= (const float*)d_in[1]; const float* b1k=(const float*)d_in[2];
  const float* W1w= (const float*)d_in[3]; const float* b1w=(const float*)d_in[4];
  const float* W1g= (const float*)d_in[5]; const float* b1g=(const float*)d_in[6];
  const float* W1o= (const float*)d_in[7]; const float* b1o=(const float*)d_in[8];
  const float* W2k= (const float*)d_in[9]; const float* b2k=(const float*)d_in[10];
  const float* W2w= (const float*)d_in[11]; const float* b2w=(const float*)d_in[12];
  const float* W2g= (const float*)d_in[13]; const float* b2g=(const float*)d_in[14];
  const float* W2o= (const float*)d_in[15]; const float* b2o=(const float*)d_in[16];

  float* ws = (float*)d_ws;
  float* P1     = ws;                 // 2*512*32*12    = 393216 floats
  float* SM     = P1 + 393216;        // 512*64*8*4     = 1048576 floats
  float* O1last = SM + 1048576;       // 64*512         = 32768
  float* R2F    = O1last + 32768;     // 3*64           = 192
  float* Opart  = R2F + 192;          // 64*128         = 8192
  unsigned short* W1oTb = (unsigned short*)(Opart + 8192);  // 512*128 bf16
  unsigned short* W2cTb = W1oTb + 65536;                    // 16*512 bf16
  float* P2     = P1;   // alias: P1 dead after k_scan1 (k_fused reads only X & SM)
  float* out    = (float*)d_out;

  hipLaunchKernelGGL(k_proj1, dim3(768), dim3(256), 0, stream,
                     X, W1k,b1k, W1w,b1w, W1g,b1g, P1,
                     W1o, W2k, W2w, W2g, W1oTb, W2cTb);
  hipLaunchKernelGGL(k_scan1, dim3(2), dim3(576), 0, stream, P1, SM);
  hipLaunchKernelGGL(k_fused, dim3(512), dim3(256), 0, stream,
                     X, W1o, b1o, SM, W1oTb, W2cTb, b2k, b2w, b2g, P2, O1last);
  hipLaunchKernelGGL(k_scan2_opart, dim3(66), dim3(576), 0, stream,
                     P2, R2F, O1last, W2o, b2o, Opart);
  hipLaunchKernelGGL(k_final, dim3(32), dim3(256), 0, stream,
                     Opart, R2F, W2o, out);
}